// Round 3
// baseline (564.769 us; speedup 1.0000x reference)
//
#include <hip/hip_runtime.h>
#include <hip/hip_bf16.h>
#include <math.h>

#define NBATCH 16
#define NW 64
#define WA 49
#define NTOK (NBATCH*NW*WA)   // 50176
#define CCH 384
#define HIDDEN 1536

typedef __attribute__((ext_vector_type(8))) short short8;
typedef __attribute__((ext_vector_type(4))) float floatx4;

static __device__ __forceinline__ short f2bf(float f){
  unsigned u = __float_as_uint(f);
  unsigned r = (u + 0x7fff + ((u>>16)&1)) >> 16;
  return (short)r;
}
static __device__ __forceinline__ float bf2f(short s){
  return __uint_as_float(((unsigned)(unsigned short)s)<<16);
}

static __device__ __forceinline__ void gload16(const void* g, void* l){
  __builtin_amdgcn_global_load_lds(
      (const __attribute__((address_space(1))) void*)g,
      (__attribute__((address_space(3))) void*)l, 16, 0, 0);
}

// token index -> pixel index (same map for LN1 gather and proj scatter)
static __device__ __forceinline__ int tok2pix(int t){
  int b = t / (NW*WA);
  int rem = t % (NW*WA);
  int w = rem / WA, a = rem % WA;
  int hs = (w>>3)*7 + a/7;
  int ws = (w&7)*7 + a%7;
  int hp = hs + 3; if (hp >= 56) hp -= 56;
  int wp = ws + 3; if (wp >= 56) wp -= 56;
  return (b*56 + hp)*56 + wp;
}

// ---- weight transpose + fp32->bf16 convert: W[K,N] -> Wt[N,K] ----
__global__ void wtconv(const float* __restrict__ W, short* __restrict__ Wt, int K, int N){
  int i = blockIdx.x*256 + threadIdx.x;
  if (i >= K*N) return;
  int k = i / N, n = i % N;
  Wt[(size_t)n*K + k] = f2bf(W[i]);
}

// ---- LayerNorm (one wave per token). MAP=1: gather via tok2pix (LN1+shift+window) ----
template<int MAP>
__global__ __launch_bounds__(256) void ln_kernel(const float* __restrict__ x,
    const float* __restrict__ g, const float* __restrict__ bta, short* __restrict__ out){
  int wid = threadIdx.x>>6, lane = threadIdx.x&63;
  int t = blockIdx.x*4 + wid;
  const float* row = x + (size_t)(MAP ? tok2pix(t) : t)*CCH;
  float v[6]; float s=0.f, ss=0.f;
  #pragma unroll
  for (int i=0;i<6;i++){ float f=row[lane+64*i]; v[i]=f; s+=f; ss+=f*f; }
  #pragma unroll
  for (int off=32; off; off>>=1){ s += __shfl_xor(s,off); ss += __shfl_xor(ss,off); }
  float mean = s*(1.f/384.f);
  float var  = ss*(1.f/384.f) - mean*mean;
  float inv  = rsqrtf(var + 1e-5f);
  short* orow = out + (size_t)t*CCH;
  #pragma unroll
  for (int i=0;i<6;i++){ int c=lane+64*i; orow[c] = f2bf((v[i]-mean)*inv*g[c]+bta[c]); }
}

// ---- 8-wave pipelined bf16 MFMA GEMM (T2+T3/T4+T5+T1):
// BM=256, BN=128, BK=64, wave tile 64x64, double-buffered LDS w/ XOR swizzle,
// counted vmcnt(6), setprio around MFMA clusters, bijective XCD blockIdx swizzle.
// C[M,N] = A[M,K]*Bt[N,K]^T + bias, fused epilogues:
// EPI 0: store bf16 (qkv)      EPI 1: proj -> y[pix] = x[pix] + v
// EPI 2: gelu -> bf16 (fc1)    EPI 3: out[t] = res[t] + v (fc2, fp32)
template<int EPI>
__global__ __launch_bounds__(512) void gemm8(const short* __restrict__ A,
    const short* __restrict__ Bt, const float* __restrict__ bias,
    const float* __restrict__ res, void* __restrict__ outp,
    int M, int N, int K, int gx)
{
  __shared__ short As[2][256][64];
  __shared__ short Bs[2][128][64];
  const int tid = threadIdx.x, lane = tid & 63, wid = tid >> 6;
  const int fr = lane & 15, fg = lane >> 4;
  const int wm = wid >> 1, wn = wid & 1;

  // bijective XCD swizzle (m204), then colblk-fastest so same-A-panel blocks share an XCD
  const int nwg = gridDim.x;
  const int q = nwg >> 3, r = nwg & 7;
  const int xcd = blockIdx.x & 7, pos = blockIdx.x >> 3;
  const int wgid = (xcd < r ? xcd*(q+1) : r*(q+1) + (xcd-r)*q) + pos;
  const int m0 = (wgid / gx) * 256, n0 = (wgid % gx) * 128;

  floatx4 acc[4][4];
  #pragma unroll
  for (int m=0;m<4;m++)
    #pragma unroll
    for (int n=0;n<4;n++) acc[m][n] = (floatx4){0.f,0.f,0.f,0.f};

  // staging: thread -> (row = tid>>3 within 64-row slab, physical slot = tid&7),
  // pre-swizzled GLOBAL column so read-side XOR sees logical data (rule #21)
  const int srow = tid >> 3;
  const int scol = ((tid & 7) ^ (srow & 7)) * 8;
  const short* gA = A  + (size_t)(m0 + srow) * K + scol;
  const short* gB = Bt + (size_t)(n0 + srow) * K + scol;
  const size_t a64 = (size_t)64 * K;
  short* aB = &As[0][wid*8][0];   // wave-uniform LDS bases (HW adds lane*16B)
  short* bB = &Bs[0][wid*8][0];
  const int nt = K >> 6;

#define STAGE(tt, bb) do{                                            \
    const int k0_ = (tt) << 6;                                       \
    short* a_ = aB + (bb)*256*64;                                     \
    short* b_ = bB + (bb)*128*64;                                     \
    gload16(gA + k0_,          a_);                                   \
    gload16(gA + k0_ +   a64,  a_ +  64*64);                          \
    gload16(gA + k0_ + 2*a64,  a_ + 128*64);                          \
    gload16(gA + k0_ + 3*a64,  a_ + 192*64);                          \
    gload16(gB + k0_,          b_);                                   \
    gload16(gB + k0_ +   a64,  b_ +  64*64);                          \
  }while(0)

  STAGE(0, 0);
  for (int t = 0; t < nt; ++t){
    const int buf = t & 1;
    if (t + 1 < nt){
      STAGE(t+1, buf^1);
      asm volatile("s_waitcnt vmcnt(6)" ::: "memory");
    } else {
      asm volatile("s_waitcnt vmcnt(0)" ::: "memory");
    }
    __builtin_amdgcn_s_barrier();
    #pragma unroll
    for (int kk=0; kk<2; ++kk){
      short8 af[4], bq[4];
      #pragma unroll
      for (int m=0;m<4;m++)
        af[m] = *(const short8*)&As[buf][wm*64 + m*16 + fr][(((kk<<2)|fg) ^ (fr&7)) << 3];
      #pragma unroll
      for (int n=0;n<4;n++)
        bq[n] = *(const short8*)&Bs[buf][wn*64 + n*16 + fr][(((kk<<2)|fg) ^ (fr&7)) << 3];
      __builtin_amdgcn_s_setprio(1);
      #pragma unroll
      for (int m=0;m<4;m++)
        #pragma unroll
        for (int n=0;n<4;n++)
          acc[m][n] = __builtin_amdgcn_mfma_f32_16x16x32_bf16(af[m], bq[n], acc[m][n], 0,0,0);
      __builtin_amdgcn_s_setprio(0);
      if (kk==0) __builtin_amdgcn_s_barrier();
    }
    __builtin_amdgcn_s_barrier();
  }
#undef STAGE

  #pragma unroll
  for (int n=0;n<4;n++){
    int gc = n0 + wn*64 + n*16 + fr;
    float bv = bias[gc];
    #pragma unroll
    for (int m=0;m<4;m++){
      int gr0 = m0 + wm*64 + m*16 + fg*4;
      #pragma unroll
      for (int i=0;i<4;i++){
        int R = gr0 + i;
        float v = acc[m][n][i] + bv;
        if (EPI==0){
          ((short*)outp)[(size_t)R*N + gc] = f2bf(v);
        } else if (EPI==1){
          int p = tok2pix(R); size_t idx=(size_t)p*CCH+gc;
          ((float*)outp)[idx] = res[idx] + v;
        } else if (EPI==2){
          float gg = 0.5f*v*(1.f+erff(v*0.70710678118654752f));
          ((short*)outp)[(size_t)R*N+gc] = f2bf(gg);
        } else {
          size_t idx=(size_t)R*CCH+gc;
          ((float*)outp)[idx] = res[idx] + v;
        }
      }
    }
  }
}

// ---- MFMA windowed attention: block = window, wave w -> heads w, w+4, w+8 ----
__global__ __launch_bounds__(256) void attn_mfma(const short* __restrict__ qkv,
    const float* __restrict__ rel_bias, short* __restrict__ attnout)
{
  __shared__ short Pl[4][64][68];
  __shared__ short Vt[4][32][68];
  __shared__ float lb[4][169];
  __shared__ int grp[64];
  const int wi = blockIdx.x;
  const int wid = threadIdx.x>>6, lane = threadIdx.x&63;
  const int fr = lane&15, fg = lane>>4;
  const int w = wi & 63, wh = w>>3, ww = w&7;
  if (threadIdx.x < 64){
    int t = threadIdx.x;
    int gv = 0;
    if (t < 49){
      int ai = t/7, aj = t%7;
      int hs = wh*7+ai, ws = ww*7+aj;
      int gh = hs<49?0:(hs<53?1:2);
      int gw = ws<49?0:(ws<53?1:2);
      gv = gh*3+gw;
    } else gv = -1;
    grp[t] = gv;
  }
  for (int t = lane; t < 32*15; t += 64){
    int d = t/15, j = 49 + t - d*15;
    Vt[wid][d][j] = 0;
  }
  __syncthreads();
  const size_t tbase = (size_t)wi*49;
  const float SCALE = 0.17677669529663687f;

  for (int hi=0; hi<3; ++hi){
    const int h = hi*4 + wid;
    for (int t = lane; t < 169; t += 64) lb[wid][t] = rel_bias[t*12 + h];
    for (int t = lane; t < 196; t += 64){
      int j = t>>2, d0 = (t&3)*8;
      short8 vv = *(const short8*)&qkv[(tbase+j)*1152 + 768 + h*32 + d0];
      #pragma unroll
      for (int s=0;s<8;s++) Vt[wid][d0+s][j] = vv[s];
    }
    short8 zf = {};
    short8 aq[4], bk[4];
    #pragma unroll
    for (int m=0;m<4;m++){
      int r = m*16+fr;
      aq[m] = (r<49) ? *(const short8*)&qkv[(tbase+r)*1152       + h*32 + fg*8] : zf;
      bk[m] = (r<49) ? *(const short8*)&qkv[(tbase+r)*1152 + 384 + h*32 + fg*8] : zf;
    }
    __syncthreads();   // (1) Vt/lb visible

    floatx4 sc[4][4];
    #pragma unroll
    for (int m=0;m<4;m++)
      #pragma unroll
      for (int n=0;n<4;n++)
        sc[m][n] = __builtin_amdgcn_mfma_f32_16x16x32_bf16(aq[m], bk[n], (floatx4){0.f,0.f,0.f,0.f}, 0,0,0);

    int ciC[4], cjC[4], gC[4], cvC[4];
    #pragma unroll
    for (int n=0;n<4;n++){
      int c = n*16+fr;
      ciC[n] = c/7; cjC[n] = c - ciC[n]*7;
      gC[n] = grp[c]; cvC[n] = (c<49);
    }
    #pragma unroll
    for (int m=0;m<4;m++){
      #pragma unroll
      for (int i=0;i<4;i++){
        int r = m*16 + fg*4 + i;
        int rv = (r<49);
        int ri = r/7, rj = r - ri*7;
        int gr = grp[r];
        float mxv = -3e30f;
        #pragma unroll
        for (int n=0;n<4;n++){
          float s;
          if (rv && cvC[n]){
            int dr = ri - ciC[n] + 6, dc = rj - cjC[n] + 6;
            s = sc[m][n][i]*SCALE + lb[wid][dr*13+dc];
            if (gr != gC[n]) s -= 100.f;
          } else s = -3e30f;
          sc[m][n][i] = s;
          mxv = fmaxf(mxv, s);
        }
        #pragma unroll
        for (int off=1;off<16;off<<=1) mxv = fmaxf(mxv, __shfl_xor(mxv, off));
        float sum = 0.f;
        #pragma unroll
        for (int n=0;n<4;n++){
          float e = __expf(sc[m][n][i]-mxv);
          sc[m][n][i] = e; sum += e;
        }
        #pragma unroll
        for (int off=1;off<16;off<<=1) sum += __shfl_xor(sum, off);
        float inv = 1.f/sum;
        #pragma unroll
        for (int n=0;n<4;n++)
          Pl[wid][r][n*16+fr] = f2bf(sc[m][n][i]*inv);
      }
    }
    __syncthreads();   // (2) P visible

    short8 pa[4][2], vb[2][2];
    #pragma unroll
    for (int m=0;m<4;m++)
      #pragma unroll
      for (int ks=0;ks<2;ks++)
        pa[m][ks] = *(const short8*)&Pl[wid][m*16+fr][ks*32+fg*8];
    #pragma unroll
    for (int n2=0;n2<2;n2++)
      #pragma unroll
      for (int ks=0;ks<2;ks++)
        vb[n2][ks] = *(const short8*)&Vt[wid][n2*16+fr][ks*32+fg*8];
    floatx4 oc[4][2];
    #pragma unroll
    for (int m=0;m<4;m++)
      #pragma unroll
      for (int n2=0;n2<2;n2++){
        oc[m][n2] = (floatx4){0.f,0.f,0.f,0.f};
        #pragma unroll
        for (int ks=0;ks<2;ks++)
          oc[m][n2] = __builtin_amdgcn_mfma_f32_16x16x32_bf16(pa[m][ks], vb[n2][ks], oc[m][n2], 0,0,0);
      }
    #pragma unroll
    for (int m=0;m<4;m++){
      #pragma unroll
      for (int i=0;i<4;i++){
        int r = m*16 + fg*4 + i;
        if (r < 49){
          #pragma unroll
          for (int n2=0;n2<2;n2++)
            attnout[(tbase+r)*384 + h*32 + n2*16 + fr] = f2bf(oc[m][n2][i]);
        }
      }
    }
    __syncthreads();   // (3) Vt reads done before next head's staging
  }
}

extern "C" void kernel_launch(void* const* d_in, const int* in_sizes, int n_in,
                              void* d_out, int out_size, void* d_ws, size_t ws_size,
                              hipStream_t stream)
{
  const float* x      = (const float*)d_in[0];
  const float* n1g    = (const float*)d_in[1];
  const float* n1b    = (const float*)d_in[2];
  const float* qkv_w  = (const float*)d_in[3];
  const float* qkv_b  = (const float*)d_in[4];
  const float* relb   = (const float*)d_in[5];
  const float* proj_w = (const float*)d_in[6];
  const float* proj_b = (const float*)d_in[7];
  const float* n2g    = (const float*)d_in[8];
  const float* n2b    = (const float*)d_in[9];
  const float* fc1_w  = (const float*)d_in[10];
  const float* fc1_b  = (const float*)d_in[11];
  const float* fc2_w  = (const float*)d_in[12];
  const float* fc2_b  = (const float*)d_in[13];

  char* ws = (char*)d_ws;
  const size_t SZ_XW  = (size_t)NTOK*CCH*2;
  const size_t SZ_QKV = (size_t)NTOK*1152*2;
  const size_t SZ_ATT = SZ_XW;
  const size_t SZ_Y   = (size_t)NTOK*CCH*4;

  short* xw    = (short*)(ws);
  short* qkvb  = (short*)(ws + SZ_XW);
  short* att   = (short*)(ws + SZ_XW + SZ_QKV);
  float* y     = (float*)(ws + SZ_XW + SZ_QKV + SZ_ATT);
  short* wbuf  = (short*)(ws + SZ_XW + SZ_QKV + SZ_ATT + SZ_Y);
  short* qkvWt = wbuf;                           // [1152][384]
  short* projWt= qkvWt + (size_t)1152*384;       // [384][384]
  short* fc1Wt = projWt + (size_t)384*384;       // [1536][384]
  short* fc2Wt = fc1Wt + (size_t)1536*384;       // [384][1536]
  short* hbuf  = qkvb;                           // [NTOK][1536]
  short* hin   = xw;                             // [NTOK][384]

  wtconv<<<dim3((384*1152+255)/256), dim3(256), 0, stream>>>(qkv_w, qkvWt, 384, 1152);
  wtconv<<<dim3((384*384 +255)/256), dim3(256), 0, stream>>>(proj_w, projWt, 384, 384);
  wtconv<<<dim3((384*1536+255)/256), dim3(256), 0, stream>>>(fc1_w, fc1Wt, 384, 1536);
  wtconv<<<dim3((1536*384+255)/256), dim3(256), 0, stream>>>(fc2_w, fc2Wt, 1536, 384);

  ln_kernel<1><<<dim3(NTOK/4), dim3(256), 0, stream>>>(x, n1g, n1b, xw);
  gemm8<0><<<dim3(9*196),  dim3(512), 0, stream>>>(xw,  qkvWt, qkv_b, nullptr, qkvb, NTOK, 1152, 384, 9);
  attn_mfma<<<dim3(NBATCH*NW), dim3(256), 0, stream>>>(qkvb, relb, att);
  gemm8<1><<<dim3(3*196),  dim3(512), 0, stream>>>(att, projWt, proj_b, x, y, NTOK, 384, 384, 3);
  ln_kernel<0><<<dim3(NTOK/4), dim3(256), 0, stream>>>(y, n2g, n2b, hin);
  gemm8<2><<<dim3(12*196), dim3(512), 0, stream>>>(hin, fc1Wt, fc1_b, nullptr, hbuf, NTOK, 1536, 384, 12);
  gemm8<3><<<dim3(3*196),  dim3(512), 0, stream>>>(hbuf, fc2Wt, fc2_b, y, d_out, NTOK, 384, 1536, 3);
}

// Round 4
// 500.229 us; speedup vs baseline: 1.1290x; 1.1290x over previous
//
#include <hip/hip_runtime.h>
#include <hip/hip_bf16.h>
#include <math.h>

#define NBATCH 16
#define NW 64
#define WA 49
#define NTOK (NBATCH*NW*WA)   // 50176
#define CCH 384
#define HIDDEN 1536

typedef __attribute__((ext_vector_type(8))) short short8;
typedef __attribute__((ext_vector_type(4))) float floatx4;

static __device__ __forceinline__ short f2bf(float f){
  unsigned u = __float_as_uint(f);
  unsigned r = (u + 0x7fff + ((u>>16)&1)) >> 16;
  return (short)r;
}
static __device__ __forceinline__ float bf2f(short s){
  return __uint_as_float(((unsigned)(unsigned short)s)<<16);
}

static __device__ __forceinline__ void gload16(const void* g, void* l){
  __builtin_amdgcn_global_load_lds(
      (const __attribute__((address_space(1))) void*)g,
      (__attribute__((address_space(3))) void*)l, 16, 0, 0);
}

// opaque LDS read: compiler cannot see the global_load_lds -> ds_read dependence,
// so it cannot insert a conservative s_waitcnt vmcnt(0). We own the waitcnts.
static __device__ __forceinline__ short8 ds_read_b128s(unsigned addr){
  short8 r;
  asm volatile("ds_read_b128 %0, %1" : "=v"(r) : "v"(addr));
  return r;
}

// token index -> pixel index (same map for LN1 gather and proj scatter)
static __device__ __forceinline__ int tok2pix(int t){
  int b = t / (NW*WA);
  int rem = t % (NW*WA);
  int w = rem / WA, a = rem % WA;
  int hs = (w>>3)*7 + a/7;
  int ws = (w&7)*7 + a%7;
  int hp = hs + 3; if (hp >= 56) hp -= 56;
  int wp = ws + 3; if (wp >= 56) wp -= 56;
  return (b*56 + hp)*56 + wp;
}

// ---- weight transpose + fp32->bf16 convert: W[K,N] -> Wt[N,K] ----
__global__ void wtconv(const float* __restrict__ W, short* __restrict__ Wt, int K, int N){
  int i = blockIdx.x*256 + threadIdx.x;
  if (i >= K*N) return;
  int k = i / N, n = i % N;
  Wt[(size_t)n*K + k] = f2bf(W[i]);
}

// ---- LayerNorm (one wave per token). MAP=1: gather via tok2pix (LN1+shift+window) ----
template<int MAP>
__global__ __launch_bounds__(256) void ln_kernel(const float* __restrict__ x,
    const float* __restrict__ g, const float* __restrict__ bta, short* __restrict__ out){
  int wid = threadIdx.x>>6, lane = threadIdx.x&63;
  int t = blockIdx.x*4 + wid;
  const float* row = x + (size_t)(MAP ? tok2pix(t) : t)*CCH;
  float v[6]; float s=0.f, ss=0.f;
  #pragma unroll
  for (int i=0;i<6;i++){ float f=row[lane+64*i]; v[i]=f; s+=f; ss+=f*f; }
  #pragma unroll
  for (int off=32; off; off>>=1){ s += __shfl_xor(s,off); ss += __shfl_xor(ss,off); }
  float mean = s*(1.f/384.f);
  float var  = ss*(1.f/384.f) - mean*mean;
  float inv  = rsqrtf(var + 1e-5f);
  short* orow = out + (size_t)t*CCH;
  #pragma unroll
  for (int i=0;i<6;i++){ int c=lane+64*i; orow[c] = f2bf((v[i]-mean)*inv*g[c]+bta[c]); }
}

// ---- 4-wave pipelined bf16 MFMA GEMM, 2-deep prefetch, triple-buffered LDS.
// BM=128, BN=64, BK=64, wave tile 64x32, XOR-swizzled LDS (0 conflicts),
// counted vmcnt(12) (2 stages in flight), asm ds_read (opaque to compiler),
// 72 KB LDS -> 2 blocks/CU for cross-block latency hiding.
// C[M,N] = A[M,K]*Bt[N,K]^T + bias, fused epilogues:
// EPI 0: store bf16 (qkv)      EPI 1: proj -> y[pix] = x[pix] + v
// EPI 2: gelu -> bf16 (fc1)    EPI 3: out[t] = res[t] + v (fc2, fp32)
template<int EPI>
__global__ __launch_bounds__(256) void gemm8(const short* __restrict__ A,
    const short* __restrict__ Bt, const float* __restrict__ bias,
    const float* __restrict__ res, void* __restrict__ outp,
    int M, int N, int K, int gx)
{
  __shared__ short As[3][128][64];   // 48 KB
  __shared__ short Bs[3][64][64];    // 24 KB
  const int tid = threadIdx.x, lane = tid & 63, wid = tid >> 6;
  const int fr = lane & 15, fg = lane >> 4;
  const int wm = wid >> 1, wn = wid & 1;

  // bijective XCD swizzle (m204); wgid%gx = n-block fastest -> consecutive wgid
  // on one XCD share the same A row-panel (A fetched once per XCD-L2).
  const int nwg = gridDim.x;
  const int q = nwg >> 3, r = nwg & 7;
  const int xcd = blockIdx.x & 7, pos = blockIdx.x >> 3;
  const int wgid = (xcd < r ? xcd*(q+1) : r*(q+1) + (xcd-r)*q) + pos;
  const int m0 = (wgid / gx) * 128, n0 = (wgid % gx) * 64;

  floatx4 acc[4][2];
  #pragma unroll
  for (int m=0;m<4;m++)
    #pragma unroll
    for (int n=0;n<2;n++) acc[m][n] = (floatx4){0.f,0.f,0.f,0.f};

  // staging: slot index = tid within a 32-row slab; pre-swizzled GLOBAL column
  // so the read-side XOR sees logical data (both-sides-or-neither, rule #21)
  const int srow = tid >> 3;
  const int scol = ((tid & 7) ^ (srow & 7)) * 8;
  const short* gA = A  + (size_t)(m0 + srow) * K + scol;
  const short* gB = Bt + (size_t)(n0 + srow) * K + scol;
  const size_t a32 = (size_t)32 * K;
  short* aB = &As[0][wid*8][0];   // wave-uniform LDS bases (HW adds lane*16B)
  short* bB = &Bs[0][wid*8][0];
  const int nt = K >> 6;

  const unsigned aLds = (unsigned)(uintptr_t)&As[0][0][0];
  const unsigned bLds = (unsigned)(uintptr_t)&Bs[0][0][0];
  const unsigned rowOffA = (unsigned)((wm*64 + fr)*128);
  const unsigned rowOffB = (unsigned)((wn*32 + fr)*128);
  const unsigned pc0 = (unsigned)(((fg  ) ^ (fr&7))*16);
  const unsigned pc1 = (unsigned)(((4+fg) ^ (fr&7))*16);

#define STAGE(tt, bb) do{                                             \
    const size_t k0_ = (size_t)((tt) << 6);                           \
    short* a_ = aB + (size_t)(bb)*128*64;                             \
    short* b_ = bB + (size_t)(bb)*64*64;                              \
    gload16(gA + k0_,          a_);                                   \
    gload16(gA + k0_ +   a32,  a_ + 32*64);                           \
    gload16(gA + k0_ + 2*a32,  a_ + 64*64);                           \
    gload16(gA + k0_ + 3*a32,  a_ + 96*64);                           \
    gload16(gB + k0_,          b_);                                   \
    gload16(gB + k0_ +   a32,  b_ + 32*64);                           \
  }while(0)

  STAGE(0, 0);
  STAGE(1, 1);
  int rb = 0, wb = 2;
  for (int t = 0; t < nt; ++t){
    if (t + 2 < nt){
      STAGE(t+2, wb);
      asm volatile("s_waitcnt vmcnt(12)" ::: "memory");  // stage t landed; t+1,t+2 in flight
    } else if (t + 1 < nt){
      asm volatile("s_waitcnt vmcnt(6)" ::: "memory");
    } else {
      asm volatile("s_waitcnt vmcnt(0)" ::: "memory");
    }
    __builtin_amdgcn_s_barrier();      // all waves' stage-t writes visible
    const unsigned aoff = aLds + (unsigned)rb*16384u + rowOffA;
    const unsigned boff = bLds + (unsigned)rb*8192u  + rowOffB;
    #pragma unroll
    for (int kk=0; kk<2; ++kk){
      const unsigned pc = kk ? pc1 : pc0;
      short8 af[4], bq[2];
      #pragma unroll
      for (int m=0;m<4;m++) af[m] = ds_read_b128s(aoff + (unsigned)(m*2048) + pc);
      #pragma unroll
      for (int n=0;n<2;n++) bq[n] = ds_read_b128s(boff + (unsigned)(n*2048) + pc);
      asm volatile("s_waitcnt lgkmcnt(0)" ::: "memory");
      __builtin_amdgcn_sched_barrier(0);                 // rule #18: pin MFMA below the wait
      __builtin_amdgcn_s_setprio(1);
      #pragma unroll
      for (int m=0;m<4;m++)
        #pragma unroll
        for (int n=0;n<2;n++)
          acc[m][n] = __builtin_amdgcn_mfma_f32_16x16x32_bf16(af[m], bq[n], acc[m][n], 0,0,0);
      __builtin_amdgcn_s_setprio(0);
    }
    __builtin_amdgcn_s_barrier();      // reads of buf rb done before it is re-staged
    rb = (rb+1 == 3) ? 0 : rb+1;
    wb = (wb+1 == 3) ? 0 : wb+1;
  }
#undef STAGE

  #pragma unroll
  for (int n=0;n<2;n++){
    int gc = n0 + wn*32 + n*16 + fr;
    float bv = bias[gc];
    #pragma unroll
    for (int m=0;m<4;m++){
      int gr0 = m0 + wm*64 + m*16 + fg*4;
      #pragma unroll
      for (int i=0;i<4;i++){
        int R = gr0 + i;
        float v = acc[m][n][i] + bv;
        if (EPI==0){
          ((short*)outp)[(size_t)R*N + gc] = f2bf(v);
        } else if (EPI==1){
          int p = tok2pix(R); size_t idx=(size_t)p*CCH+gc;
          ((float*)outp)[idx] = res[idx] + v;
        } else if (EPI==2){
          float gg = 0.5f*v*(1.f+erff(v*0.70710678118654752f));
          ((short*)outp)[(size_t)R*N+gc] = f2bf(gg);
        } else {
          size_t idx=(size_t)R*CCH+gc;
          ((float*)outp)[idx] = res[idx] + v;
        }
      }
    }
  }
}

// ---- MFMA windowed attention: block = window, wave w -> heads w, w+4, w+8 ----
__global__ __launch_bounds__(256) void attn_mfma(const short* __restrict__ qkv,
    const float* __restrict__ rel_bias, short* __restrict__ attnout)
{
  __shared__ short Pl[4][64][68];
  __shared__ short Vt[4][32][68];
  __shared__ float lb[4][169];
  __shared__ int grp[64];
  const int wi = blockIdx.x;
  const int wid = threadIdx.x>>6, lane = threadIdx.x&63;
  const int fr = lane&15, fg = lane>>4;
  const int w = wi & 63, wh = w>>3, ww = w&7;
  if (threadIdx.x < 64){
    int t = threadIdx.x;
    int gv = 0;
    if (t < 49){
      int ai = t/7, aj = t%7;
      int hs = wh*7+ai, ws = ww*7+aj;
      int gh = hs<49?0:(hs<53?1:2);
      int gw = ws<49?0:(ws<53?1:2);
      gv = gh*3+gw;
    } else gv = -1;
    grp[t] = gv;
  }
  for (int t = lane; t < 32*15; t += 64){
    int d = t/15, j = 49 + t - d*15;
    Vt[wid][d][j] = 0;
  }
  __syncthreads();
  const size_t tbase = (size_t)wi*49;
  const float SCALE = 0.17677669529663687f;

  for (int hi=0; hi<3; ++hi){
    const int h = hi*4 + wid;
    for (int t = lane; t < 169; t += 64) lb[wid][t] = rel_bias[t*12 + h];
    for (int t = lane; t < 196; t += 64){
      int j = t>>2, d0 = (t&3)*8;
      short8 vv = *(const short8*)&qkv[(tbase+j)*1152 + 768 + h*32 + d0];
      #pragma unroll
      for (int s=0;s<8;s++) Vt[wid][d0+s][j] = vv[s];
    }
    short8 zf = {};
    short8 aq[4], bk[4];
    #pragma unroll
    for (int m=0;m<4;m++){
      int r = m*16+fr;
      aq[m] = (r<49) ? *(const short8*)&qkv[(tbase+r)*1152       + h*32 + fg*8] : zf;
      bk[m] = (r<49) ? *(const short8*)&qkv[(tbase+r)*1152 + 384 + h*32 + fg*8] : zf;
    }
    __syncthreads();   // (1) Vt/lb visible

    floatx4 sc[4][4];
    #pragma unroll
    for (int m=0;m<4;m++)
      #pragma unroll
      for (int n=0;n<4;n++)
        sc[m][n] = __builtin_amdgcn_mfma_f32_16x16x32_bf16(aq[m], bk[n], (floatx4){0.f,0.f,0.f,0.f}, 0,0,0);

    int ciC[4], cjC[4], gC[4], cvC[4];
    #pragma unroll
    for (int n=0;n<4;n++){
      int c = n*16+fr;
      ciC[n] = c/7; cjC[n] = c - ciC[n]*7;
      gC[n] = grp[c]; cvC[n] = (c<49);
    }
    #pragma unroll
    for (int m=0;m<4;m++){
      #pragma unroll
      for (int i=0;i<4;i++){
        int r = m*16 + fg*4 + i;
        int rv = (r<49);
        int ri = r/7, rj = r - ri*7;
        int gr = grp[r];
        float mxv = -3e30f;
        #pragma unroll
        for (int n=0;n<4;n++){
          float s;
          if (rv && cvC[n]){
            int dr = ri - ciC[n] + 6, dc = rj - cjC[n] + 6;
            s = sc[m][n][i]*SCALE + lb[wid][dr*13+dc];
            if (gr != gC[n]) s -= 100.f;
          } else s = -3e30f;
          sc[m][n][i] = s;
          mxv = fmaxf(mxv, s);
        }
        #pragma unroll
        for (int off=1;off<16;off<<=1) mxv = fmaxf(mxv, __shfl_xor(mxv, off));
        float sum = 0.f;
        #pragma unroll
        for (int n=0;n<4;n++){
          float e = __expf(sc[m][n][i]-mxv);
          sc[m][n][i] = e; sum += e;
        }
        #pragma unroll
        for (int off=1;off<16;off<<=1) sum += __shfl_xor(sum, off);
        float inv = 1.f/sum;
        #pragma unroll
        for (int n=0;n<4;n++)
          Pl[wid][r][n*16+fr] = f2bf(sc[m][n][i]*inv);
      }
    }
    __syncthreads();   // (2) P visible

    short8 pa[4][2], vb[2][2];
    #pragma unroll
    for (int m=0;m<4;m++)
      #pragma unroll
      for (int ks=0;ks<2;ks++)
        pa[m][ks] = *(const short8*)&Pl[wid][m*16+fr][ks*32+fg*8];
    #pragma unroll
    for (int n2=0;n2<2;n2++)
      #pragma unroll
      for (int ks=0;ks<2;ks++)
        vb[n2][ks] = *(const short8*)&Vt[wid][n2*16+fr][ks*32+fg*8];
    floatx4 oc[4][2];
    #pragma unroll
    for (int m=0;m<4;m++)
      #pragma unroll
      for (int n2=0;n2<2;n2++){
        oc[m][n2] = (floatx4){0.f,0.f,0.f,0.f};
        #pragma unroll
        for (int ks=0;ks<2;ks++)
          oc[m][n2] = __builtin_amdgcn_mfma_f32_16x16x32_bf16(pa[m][ks], vb[n2][ks], oc[m][n2], 0,0,0);
      }
    #pragma unroll
    for (int m=0;m<4;m++){
      #pragma unroll
      for (int i=0;i<4;i++){
        int r = m*16 + fg*4 + i;
        if (r < 49){
          #pragma unroll
          for (int n2=0;n2<2;n2++)
            attnout[(tbase+r)*384 + h*32 + n2*16 + fr] = f2bf(oc[m][n2][i]);
        }
      }
    }
    __syncthreads();   // (3) Vt reads done before next head's staging
  }
}

extern "C" void kernel_launch(void* const* d_in, const int* in_sizes, int n_in,
                              void* d_out, int out_size, void* d_ws, size_t ws_size,
                              hipStream_t stream)
{
  const float* x      = (const float*)d_in[0];
  const float* n1g    = (const float*)d_in[1];
  const float* n1b    = (const float*)d_in[2];
  const float* qkv_w  = (const float*)d_in[3];
  const float* qkv_b  = (const float*)d_in[4];
  const float* relb   = (const float*)d_in[5];
  const float* proj_w = (const float*)d_in[6];
  const float* proj_b = (const float*)d_in[7];
  const float* n2g    = (const float*)d_in[8];
  const float* n2b    = (const float*)d_in[9];
  const float* fc1_w  = (const float*)d_in[10];
  const float* fc1_b  = (const float*)d_in[11];
  const float* fc2_w  = (const float*)d_in[12];
  const float* fc2_b  = (const float*)d_in[13];

  char* ws = (char*)d_ws;
  const size_t SZ_XW  = (size_t)NTOK*CCH*2;
  const size_t SZ_QKV = (size_t)NTOK*1152*2;
  const size_t SZ_ATT = SZ_XW;
  const size_t SZ_Y   = (size_t)NTOK*CCH*4;

  short* xw    = (short*)(ws);
  short* qkvb  = (short*)(ws + SZ_XW);
  short* att   = (short*)(ws + SZ_XW + SZ_QKV);
  float* y     = (float*)(ws + SZ_XW + SZ_QKV + SZ_ATT);
  short* wbuf  = (short*)(ws + SZ_XW + SZ_QKV + SZ_ATT + SZ_Y);
  short* qkvWt = wbuf;                           // [1152][384]
  short* projWt= qkvWt + (size_t)1152*384;       // [384][384]
  short* fc1Wt = projWt + (size_t)384*384;       // [1536][384]
  short* fc2Wt = fc1Wt + (size_t)1536*384;       // [384][1536]
  short* hbuf  = qkvb;                           // [NTOK][1536]
  short* hin   = xw;                             // [NTOK][384]

  wtconv<<<dim3((384*1152+255)/256), dim3(256), 0, stream>>>(qkv_w, qkvWt, 384, 1152);
  wtconv<<<dim3((384*384 +255)/256), dim3(256), 0, stream>>>(proj_w, projWt, 384, 384);
  wtconv<<<dim3((384*1536+255)/256), dim3(256), 0, stream>>>(fc1_w, fc1Wt, 384, 1536);
  wtconv<<<dim3((1536*384+255)/256), dim3(256), 0, stream>>>(fc2_w, fc2Wt, 1536, 384);

  ln_kernel<1><<<dim3(NTOK/4), dim3(256), 0, stream>>>(x, n1g, n1b, xw);
  gemm8<0><<<dim3(18*392), dim3(256), 0, stream>>>(xw,  qkvWt, qkv_b, nullptr, qkvb, NTOK, 1152, 384, 18);
  attn_mfma<<<dim3(NBATCH*NW), dim3(256), 0, stream>>>(qkvb, relb, att);
  gemm8<1><<<dim3(6*392),  dim3(256), 0, stream>>>(att, projWt, proj_b, x, y, NTOK, 384, 384, 6);
  ln_kernel<0><<<dim3(NTOK/4), dim3(256), 0, stream>>>(y, n2g, n2b, hin);
  gemm8<2><<<dim3(24*392), dim3(256), 0, stream>>>(hin, fc1Wt, fc1_b, nullptr, hbuf, NTOK, 1536, 384, 24);
  gemm8<3><<<dim3(6*392),  dim3(256), 0, stream>>>(hbuf, fc2Wt, fc2_b, y, d_out, NTOK, 384, 1536, 6);
}

// Round 5
// 481.439 us; speedup vs baseline: 1.1731x; 1.0390x over previous
//
#include <hip/hip_runtime.h>
#include <hip/hip_bf16.h>
#include <math.h>

#define NBATCH 16
#define NW 64
#define WA 49
#define NTOK (NBATCH*NW*WA)   // 50176
#define CCH 384
#define HIDDEN 1536

typedef __attribute__((ext_vector_type(8))) short short8;
typedef __attribute__((ext_vector_type(4))) float floatx4;

static __device__ __forceinline__ short f2bf(float f){
  unsigned u = __float_as_uint(f);
  unsigned r = (u + 0x7fff + ((u>>16)&1)) >> 16;
  return (short)r;
}
static __device__ __forceinline__ float bf2f(short s){
  return __uint_as_float(((unsigned)(unsigned short)s)<<16);
}

static __device__ __forceinline__ void gload16(const void* g, void* l){
  __builtin_amdgcn_global_load_lds(
      (const __attribute__((address_space(1))) void*)g,
      (__attribute__((address_space(3))) void*)l, 16, 0, 0);
}

// opaque LDS read: compiler cannot see the global_load_lds -> ds_read dependence,
// so it cannot insert a conservative s_waitcnt vmcnt(0). We own the waitcnts.
static __device__ __forceinline__ short8 ds_read_b128s(unsigned addr){
  short8 r;
  asm volatile("ds_read_b128 %0, %1" : "=v"(r) : "v"(addr));
  return r;
}

// token index -> pixel index (same map for LN1 gather and proj scatter)
static __device__ __forceinline__ int tok2pix(int t){
  int b = t / (NW*WA);
  int rem = t % (NW*WA);
  int w = rem / WA, a = rem % WA;
  int hs = (w>>3)*7 + a/7;
  int ws = (w&7)*7 + a%7;
  int hp = hs + 3; if (hp >= 56) hp -= 56;
  int wp = ws + 3; if (wp >= 56) wp -= 56;
  return (b*56 + hp)*56 + wp;
}

// ---- weight transpose + fp32->bf16 convert: W[K,N] -> Wt[N,K] ----
__global__ void wtconv(const float* __restrict__ W, short* __restrict__ Wt, int K, int N){
  int i = blockIdx.x*256 + threadIdx.x;
  if (i >= K*N) return;
  int k = i / N, n = i % N;
  Wt[(size_t)n*K + k] = f2bf(W[i]);
}

// ---- LayerNorm (one wave per token). MAP=1: gather via tok2pix (LN1+shift+window) ----
template<int MAP>
__global__ __launch_bounds__(256) void ln_kernel(const float* __restrict__ x,
    const float* __restrict__ g, const float* __restrict__ bta, short* __restrict__ out){
  int wid = threadIdx.x>>6, lane = threadIdx.x&63;
  int t = blockIdx.x*4 + wid;
  const float* row = x + (size_t)(MAP ? tok2pix(t) : t)*CCH;
  float v[6]; float s=0.f, ss=0.f;
  #pragma unroll
  for (int i=0;i<6;i++){ float f=row[lane+64*i]; v[i]=f; s+=f; ss+=f*f; }
  #pragma unroll
  for (int off=32; off; off>>=1){ s += __shfl_xor(s,off); ss += __shfl_xor(ss,off); }
  float mean = s*(1.f/384.f);
  float var  = ss*(1.f/384.f) - mean*mean;
  float inv  = rsqrtf(var + 1e-5f);
  short* orow = out + (size_t)t*CCH;
  #pragma unroll
  for (int i=0;i<6;i++){ int c=lane+64*i; orow[c] = f2bf((v[i]-mean)*inv*g[c]+bta[c]); }
}

// ---- 8-wave pipelined bf16 MFMA GEMM, double-buffered, 1-deep prefetch.
// BM=256, BN=64, BK=64, wave tile 64x32, XOR-swizzled LDS (0 conflicts),
// counted vmcnt(5) (next stage in flight), asm ds_read (opaque to compiler),
// 80 KB LDS -> 2 blocks/CU = 16 waves/CU.
// C[M,N] = A[M,K]*Bt[N,K]^T + bias, fused epilogues:
// EPI 0: store bf16 (qkv)      EPI 1: proj -> y[pix] = x[pix] + v
// EPI 2: gelu -> bf16 (fc1)    EPI 3: out[t] = res[t] + v (fc2, fp32)
template<int EPI>
__global__ __launch_bounds__(512) void gemm8(const short* __restrict__ A,
    const short* __restrict__ Bt, const float* __restrict__ bias,
    const float* __restrict__ res, void* __restrict__ outp,
    int M, int N, int K, int gx)
{
  __shared__ short As[2][256][64];   // 64 KB
  __shared__ short Bs[2][64][64];    // 16 KB
  const int tid = threadIdx.x, lane = tid & 63, wid = tid >> 6;
  const int fr = lane & 15, fg = lane >> 4;
  const int wm = wid >> 1, wn = wid & 1;

  // bijective XCD swizzle (m204); wgid%gx = n-block fastest -> consecutive wgid
  // on one XCD share the same A row-panel (A fetched once per XCD-L2).
  const int nwg = gridDim.x;
  const int q = nwg >> 3, r = nwg & 7;
  const int xcd = blockIdx.x & 7, pos = blockIdx.x >> 3;
  const int wgid = (xcd < r ? xcd*(q+1) : r*(q+1) + (xcd-r)*q) + pos;
  const int m0 = (wgid / gx) * 256, n0 = (wgid % gx) * 64;

  floatx4 acc[4][2];
  #pragma unroll
  for (int m=0;m<4;m++)
    #pragma unroll
    for (int n=0;n<2;n++) acc[m][n] = (floatx4){0.f,0.f,0.f,0.f};

  // staging: row = tid>>3 within a 64-row slab, physical slot = tid&7;
  // pre-swizzled GLOBAL column so read-side XOR sees logical data (rule #21)
  const int srow = tid >> 3;
  const int scol = ((tid & 7) ^ (srow & 7)) * 8;
  const short* gA = A  + (size_t)(m0 + srow) * K + scol;
  const short* gB = Bt + (size_t)(n0 + srow) * K + scol;
  const size_t a64 = (size_t)64 * K;
  short* aB = &As[0][wid*8][0];   // wave-uniform LDS bases (HW adds lane*16B)
  short* bB = &Bs[0][wid*8][0];
  const int nt = K >> 6;

  const unsigned aLds = (unsigned)(uintptr_t)&As[0][0][0];
  const unsigned bLds = (unsigned)(uintptr_t)&Bs[0][0][0];
  const unsigned rowOffA = (unsigned)((wm*64 + fr)*128);
  const unsigned rowOffB = (unsigned)((wn*32 + fr)*128);
  const unsigned pc0 = (unsigned)(((fg  ) ^ (fr&7))*16);
  const unsigned pc1 = (unsigned)(((4+fg) ^ (fr&7))*16);

#define STAGE(tt, bb) do{                                             \
    const size_t k0_ = (size_t)((tt) << 6);                           \
    short* a_ = aB + (size_t)(bb)*256*64;                             \
    short* b_ = bB + (size_t)(bb)*64*64;                              \
    gload16(gA + k0_,          a_);                                   \
    gload16(gA + k0_ +   a64,  a_ +  64*64);                          \
    gload16(gA + k0_ + 2*a64,  a_ + 128*64);                          \
    gload16(gA + k0_ + 3*a64,  a_ + 192*64);                          \
    gload16(gB + k0_,          b_);                                   \
  }while(0)

  STAGE(0, 0);
  for (int t = 0; t < nt; ++t){
    const int buf = t & 1;
    if (t + 1 < nt){
      STAGE(t+1, buf^1);
      asm volatile("s_waitcnt vmcnt(5)" ::: "memory");   // stage t landed; t+1 in flight
    } else {
      asm volatile("s_waitcnt vmcnt(0)" ::: "memory");
    }
    __builtin_amdgcn_s_barrier();      // all waves' stage-t writes visible
    const unsigned aoff = aLds + (unsigned)buf*32768u + rowOffA;
    const unsigned boff = bLds + (unsigned)buf*8192u  + rowOffB;
    #pragma unroll
    for (int kk=0; kk<2; ++kk){
      const unsigned pc = kk ? pc1 : pc0;
      short8 af[4], bq[2];
      #pragma unroll
      for (int m=0;m<4;m++) af[m] = ds_read_b128s(aoff + (unsigned)(m*2048) + pc);
      #pragma unroll
      for (int n=0;n<2;n++) bq[n] = ds_read_b128s(boff + (unsigned)(n*2048) + pc);
      asm volatile("s_waitcnt lgkmcnt(0)" ::: "memory");
      __builtin_amdgcn_sched_barrier(0);                 // rule #18: pin MFMA below the wait
      __builtin_amdgcn_s_setprio(1);
      #pragma unroll
      for (int m=0;m<4;m++)
        #pragma unroll
        for (int n=0;n<2;n++)
          acc[m][n] = __builtin_amdgcn_mfma_f32_16x16x32_bf16(af[m], bq[n], acc[m][n], 0,0,0);
      __builtin_amdgcn_s_setprio(0);
    }
    __builtin_amdgcn_s_barrier();      // reads of buf done before it is re-staged
  }
#undef STAGE

  #pragma unroll
  for (int n=0;n<2;n++){
    int gc = n0 + wn*32 + n*16 + fr;
    float bv = bias[gc];
    #pragma unroll
    for (int m=0;m<4;m++){
      int gr0 = m0 + wm*64 + m*16 + fg*4;
      #pragma unroll
      for (int i=0;i<4;i++){
        int R = gr0 + i;
        float v = acc[m][n][i] + bv;
        if (EPI==0){
          ((short*)outp)[(size_t)R*N + gc] = f2bf(v);
        } else if (EPI==1){
          int p = tok2pix(R); size_t idx=(size_t)p*CCH+gc;
          ((float*)outp)[idx] = res[idx] + v;
        } else if (EPI==2){
          // tanh-approx GELU (max dev ~3e-4 vs erf form; threshold 0.11)
          float u  = v + 0.044715f*v*v*v;
          float e  = __expf(1.5957691216057308f*u);   // e^(2*0.79788456*u)
          float th = 1.f - 2.f/(e+1.f);
          float gg = 0.5f*v*(1.f+th);
          ((short*)outp)[(size_t)R*N+gc] = f2bf(gg);
        } else {
          size_t idx=(size_t)R*CCH+gc;
          ((float*)outp)[idx] = res[idx] + v;
        }
      }
    }
  }
}

// ---- MFMA windowed attention: block = window, wave w -> heads w, w+4, w+8 ----
__global__ __launch_bounds__(256) void attn_mfma(const short* __restrict__ qkv,
    const float* __restrict__ rel_bias, short* __restrict__ attnout)
{
  __shared__ short Pl[4][64][68];
  __shared__ short Vt[4][32][68];
  __shared__ float lb[4][169];
  __shared__ int grp[64];
  const int wi = blockIdx.x;
  const int wid = threadIdx.x>>6, lane = threadIdx.x&63;
  const int fr = lane&15, fg = lane>>4;
  const int w = wi & 63, wh = w>>3, ww = w&7;
  if (threadIdx.x < 64){
    int t = threadIdx.x;
    int gv = 0;
    if (t < 49){
      int ai = t/7, aj = t%7;
      int hs = wh*7+ai, ws = ww*7+aj;
      int gh = hs<49?0:(hs<53?1:2);
      int gw = ws<49?0:(ws<53?1:2);
      gv = gh*3+gw;
    } else gv = -1;
    grp[t] = gv;
  }
  for (int t = lane; t < 32*15; t += 64){
    int d = t/15, j = 49 + t - d*15;
    Vt[wid][d][j] = 0;
  }
  __syncthreads();
  const size_t tbase = (size_t)wi*49;
  const float SCALE = 0.17677669529663687f;

  for (int hi=0; hi<3; ++hi){
    const int h = hi*4 + wid;
    for (int t = lane; t < 169; t += 64) lb[wid][t] = rel_bias[t*12 + h];
    for (int t = lane; t < 196; t += 64){
      int j = t>>2, d0 = (t&3)*8;
      short8 vv = *(const short8*)&qkv[(tbase+j)*1152 + 768 + h*32 + d0];
      #pragma unroll
      for (int s=0;s<8;s++) Vt[wid][d0+s][j] = vv[s];
    }
    short8 zf = {};
    short8 aq[4], bk[4];
    #pragma unroll
    for (int m=0;m<4;m++){
      int r = m*16+fr;
      aq[m] = (r<49) ? *(const short8*)&qkv[(tbase+r)*1152       + h*32 + fg*8] : zf;
      bk[m] = (r<49) ? *(const short8*)&qkv[(tbase+r)*1152 + 384 + h*32 + fg*8] : zf;
    }
    __syncthreads();   // (1) Vt/lb visible

    floatx4 sc[4][4];
    #pragma unroll
    for (int m=0;m<4;m++)
      #pragma unroll
      for (int n=0;n<4;n++)
        sc[m][n] = __builtin_amdgcn_mfma_f32_16x16x32_bf16(aq[m], bk[n], (floatx4){0.f,0.f,0.f,0.f}, 0,0,0);

    int ciC[4], cjC[4], gC[4], cvC[4];
    #pragma unroll
    for (int n=0;n<4;n++){
      int c = n*16+fr;
      ciC[n] = c/7; cjC[n] = c - ciC[n]*7;
      gC[n] = grp[c]; cvC[n] = (c<49);
    }
    #pragma unroll
    for (int m=0;m<4;m++){
      #pragma unroll
      for (int i=0;i<4;i++){
        int r = m*16 + fg*4 + i;
        int rv = (r<49);
        int ri = r/7, rj = r - ri*7;
        int gr = grp[r];
        float mxv = -3e30f;
        #pragma unroll
        for (int n=0;n<4;n++){
          float s;
          if (rv && cvC[n]){
            int dr = ri - ciC[n] + 6, dc = rj - cjC[n] + 6;
            s = sc[m][n][i]*SCALE + lb[wid][dr*13+dc];
            if (gr != gC[n]) s -= 100.f;
          } else s = -3e30f;
          sc[m][n][i] = s;
          mxv = fmaxf(mxv, s);
        }
        #pragma unroll
        for (int off=1;off<16;off<<=1) mxv = fmaxf(mxv, __shfl_xor(mxv, off));
        float sum = 0.f;
        #pragma unroll
        for (int n=0;n<4;n++){
          float e = __expf(sc[m][n][i]-mxv);
          sc[m][n][i] = e; sum += e;
        }
        #pragma unroll
        for (int off=1;off<16;off<<=1) sum += __shfl_xor(sum, off);
        float inv = 1.f/sum;
        #pragma unroll
        for (int n=0;n<4;n++)
          Pl[wid][r][n*16+fr] = f2bf(sc[m][n][i]*inv);
      }
    }
    __syncthreads();   // (2) P visible

    short8 pa[4][2], vb[2][2];
    #pragma unroll
    for (int m=0;m<4;m++)
      #pragma unroll
      for (int ks=0;ks<2;ks++)
        pa[m][ks] = *(const short8*)&Pl[wid][m*16+fr][ks*32+fg*8];
    #pragma unroll
    for (int n2=0;n2<2;n2++)
      #pragma unroll
      for (int ks=0;ks<2;ks++)
        vb[n2][ks] = *(const short8*)&Vt[wid][n2*16+fr][ks*32+fg*8];
    floatx4 oc[4][2];
    #pragma unroll
    for (int m=0;m<4;m++)
      #pragma unroll
      for (int n2=0;n2<2;n2++){
        oc[m][n2] = (floatx4){0.f,0.f,0.f,0.f};
        #pragma unroll
        for (int ks=0;ks<2;ks++)
          oc[m][n2] = __builtin_amdgcn_mfma_f32_16x16x32_bf16(pa[m][ks], vb[n2][ks], oc[m][n2], 0,0,0);
      }
    #pragma unroll
    for (int m=0;m<4;m++){
      #pragma unroll
      for (int i=0;i<4;i++){
        int r = m*16 + fg*4 + i;
        if (r < 49){
          #pragma unroll
          for (int n2=0;n2<2;n2++)
            attnout[(tbase+r)*384 + h*32 + n2*16 + fr] = f2bf(oc[m][n2][i]);
        }
      }
    }
    __syncthreads();   // (3) Vt reads done before next head's staging
  }
}

extern "C" void kernel_launch(void* const* d_in, const int* in_sizes, int n_in,
                              void* d_out, int out_size, void* d_ws, size_t ws_size,
                              hipStream_t stream)
{
  const float* x      = (const float*)d_in[0];
  const float* n1g    = (const float*)d_in[1];
  const float* n1b    = (const float*)d_in[2];
  const float* qkv_w  = (const float*)d_in[3];
  const float* qkv_b  = (const float*)d_in[4];
  const float* relb   = (const float*)d_in[5];
  const float* proj_w = (const float*)d_in[6];
  const float* proj_b = (const float*)d_in[7];
  const float* n2g    = (const float*)d_in[8];
  const float* n2b    = (const float*)d_in[9];
  const float* fc1_w  = (const float*)d_in[10];
  const float* fc1_b  = (const float*)d_in[11];
  const float* fc2_w  = (const float*)d_in[12];
  const float* fc2_b  = (const float*)d_in[13];

  char* ws = (char*)d_ws;
  const size_t SZ_XW  = (size_t)NTOK*CCH*2;
  const size_t SZ_QKV = (size_t)NTOK*1152*2;
  const size_t SZ_ATT = SZ_XW;
  const size_t SZ_Y   = (size_t)NTOK*CCH*4;

  short* xw    = (short*)(ws);
  short* qkvb  = (short*)(ws + SZ_XW);
  short* att   = (short*)(ws + SZ_XW + SZ_QKV);
  float* y     = (float*)(ws + SZ_XW + SZ_QKV + SZ_ATT);
  short* wbuf  = (short*)(ws + SZ_XW + SZ_QKV + SZ_ATT + SZ_Y);
  short* qkvWt = wbuf;                           // [1152][384]
  short* projWt= qkvWt + (size_t)1152*384;       // [384][384]
  short* fc1Wt = projWt + (size_t)384*384;       // [1536][384]
  short* fc2Wt = fc1Wt + (size_t)1536*384;       // [384][1536]
  short* hbuf  = qkvb;                           // [NTOK][1536]
  short* hin   = xw;                             // [NTOK][384]

  wtconv<<<dim3((384*1152+255)/256), dim3(256), 0, stream>>>(qkv_w, qkvWt, 384, 1152);
  wtconv<<<dim3((384*384 +255)/256), dim3(256), 0, stream>>>(proj_w, projWt, 384, 384);
  wtconv<<<dim3((384*1536+255)/256), dim3(256), 0, stream>>>(fc1_w, fc1Wt, 384, 1536);
  wtconv<<<dim3((1536*384+255)/256), dim3(256), 0, stream>>>(fc2_w, fc2Wt, 1536, 384);

  ln_kernel<1><<<dim3(NTOK/4), dim3(256), 0, stream>>>(x, n1g, n1b, xw);
  gemm8<0><<<dim3(18*196), dim3(512), 0, stream>>>(xw,  qkvWt, qkv_b, nullptr, qkvb, NTOK, 1152, 384, 18);
  attn_mfma<<<dim3(NBATCH*NW), dim3(256), 0, stream>>>(qkvb, relb, att);
  gemm8<1><<<dim3(6*196),  dim3(512), 0, stream>>>(att, projWt, proj_b, x, y, NTOK, 384, 384, 6);
  ln_kernel<0><<<dim3(NTOK/4), dim3(256), 0, stream>>>(y, n2g, n2b, hin);
  gemm8<2><<<dim3(24*196), dim3(512), 0, stream>>>(hin, fc1Wt, fc1_b, nullptr, hbuf, NTOK, 1536, 384, 24);
  gemm8<3><<<dim3(6*196),  dim3(512), 0, stream>>>(hbuf, fc2Wt, fc2_b, y, d_out, NTOK, 384, 1536, 6);
}

// Round 6
// 475.307 us; speedup vs baseline: 1.1882x; 1.0129x over previous
//
#include <hip/hip_runtime.h>
#include <hip/hip_bf16.h>
#include <math.h>

#define NBATCH 16
#define NW 64
#define WA 49
#define NTOK (NBATCH*NW*WA)   // 50176
#define CCH 384
#define HIDDEN 1536

typedef __attribute__((ext_vector_type(8))) short short8;
typedef __attribute__((ext_vector_type(4))) float floatx4;

static __device__ __forceinline__ short f2bf(float f){
  unsigned u = __float_as_uint(f);
  unsigned r = (u + 0x7fff + ((u>>16)&1)) >> 16;
  return (short)r;
}
static __device__ __forceinline__ float bf2f(short s){
  return __uint_as_float(((unsigned)(unsigned short)s)<<16);
}

static __device__ __forceinline__ void gload16(const void* g, void* l){
  __builtin_amdgcn_global_load_lds(
      (const __attribute__((address_space(1))) void*)g,
      (__attribute__((address_space(3))) void*)l, 16, 0, 0);
}

// opaque LDS read: compiler cannot see the global_load_lds -> ds_read dependence,
// so it cannot insert a conservative s_waitcnt vmcnt(0). We own the waitcnts.
static __device__ __forceinline__ short8 ds_read_b128s(unsigned addr){
  short8 r;
  asm volatile("ds_read_b128 %0, %1" : "=v"(r) : "v"(addr));
  return r;
}

// token index -> pixel index (same map for LN1 gather and proj scatter)
static __device__ __forceinline__ int tok2pix(int t){
  int b = t / (NW*WA);
  int rem = t % (NW*WA);
  int w = rem / WA, a = rem % WA;
  int hs = (w>>3)*7 + a/7;
  int ws = (w&7)*7 + a%7;
  int hp = hs + 3; if (hp >= 56) hp -= 56;
  int wp = ws + 3; if (wp >= 56) wp -= 56;
  return (b*56 + hp)*56 + wp;
}

// ---- weight transpose + fp32->bf16 convert: W[K,N] -> Wt[N,K] ----
__global__ void wtconv(const float* __restrict__ W, short* __restrict__ Wt, int K, int N){
  int i = blockIdx.x*256 + threadIdx.x;
  if (i >= K*N) return;
  int k = i / N, n = i % N;
  Wt[(size_t)n*K + k] = f2bf(W[i]);
}

// ---- LayerNorm (one wave per token). MAP=1: gather via tok2pix (LN1+shift+window) ----
template<int MAP>
__global__ __launch_bounds__(256) void ln_kernel(const float* __restrict__ x,
    const float* __restrict__ g, const float* __restrict__ bta, short* __restrict__ out){
  int wid = threadIdx.x>>6, lane = threadIdx.x&63;
  int t = blockIdx.x*4 + wid;
  const float* row = x + (size_t)(MAP ? tok2pix(t) : t)*CCH;
  float v[6]; float s=0.f, ss=0.f;
  #pragma unroll
  for (int i=0;i<6;i++){ float f=row[lane+64*i]; v[i]=f; s+=f; ss+=f*f; }
  #pragma unroll
  for (int off=32; off; off>>=1){ s += __shfl_xor(s,off); ss += __shfl_xor(ss,off); }
  float mean = s*(1.f/384.f);
  float var  = ss*(1.f/384.f) - mean*mean;
  float inv  = rsqrtf(var + 1e-5f);
  short* orow = out + (size_t)t*CCH;
  #pragma unroll
  for (int i=0;i<6;i++){ int c=lane+64*i; orow[c] = f2bf((v[i]-mean)*inv*g[c]+bta[c]); }
}

// ---- 8-wave pipelined bf16 MFMA GEMM, double-buffered, 1-deep prefetch.
// BM=256, BN=64, BK=64, wave tile 64x32, XOR-swizzled LDS (0 conflicts),
// counted vmcnt(5), asm ds_read, K templated -> fully-unrolled K-loop with
// immediate-offset staging (no per-step address VALU).
// C[M,N] = A[M,K]*Bt[N,K]^T + bias, fused epilogues:
// EPI 0: store bf16 (qkv)      EPI 1: proj -> y[pix] = x[pix] + v
// EPI 2: gelu -> bf16 (fc1)    EPI 3: out[t] = res[t] + v (fc2, fp32)
template<int EPI, int KK>
__global__ __launch_bounds__(512) void gemm8(const short* __restrict__ A,
    const short* __restrict__ Bt, const float* __restrict__ bias,
    const float* __restrict__ res, void* __restrict__ outp,
    int N, int gx)
{
  __shared__ short As[2][256][64];   // 64 KB
  __shared__ short Bs[2][64][64];    // 16 KB
  const int tid = threadIdx.x, lane = tid & 63, wid = tid >> 6;
  const int fr = lane & 15, fg = lane >> 4;
  const int wm = wid >> 1, wn = wid & 1;

  // bijective XCD swizzle (m204); wgid%gx = n-block fastest -> consecutive wgid
  // on one XCD share the same A row-panel (A fetched once per XCD-L2).
  const int nwg = gridDim.x;
  const int q = nwg >> 3, r = nwg & 7;
  const int xcd = blockIdx.x & 7, pos = blockIdx.x >> 3;
  const int wgid = (xcd < r ? xcd*(q+1) : r*(q+1) + (xcd-r)*q) + pos;
  const int m0 = (wgid / gx) * 256, n0 = (wgid % gx) * 64;

  floatx4 acc[4][2];
  #pragma unroll
  for (int m=0;m<4;m++)
    #pragma unroll
    for (int n=0;n<2;n++) acc[m][n] = (floatx4){0.f,0.f,0.f,0.f};

  // staging: row = tid>>3 within a 64-row slab, physical slot = tid&7;
  // pre-swizzled GLOBAL column so read-side XOR sees logical data (rule #21)
  const int srow = tid >> 3;
  const int scol = ((tid & 7) ^ (srow & 7)) * 8;
  const short* gA = A  + (size_t)(m0 + srow) * KK + scol;
  const short* gB = Bt + (size_t)(n0 + srow) * KK + scol;
  constexpr int a64 = 64 * KK;
  short* aB = &As[0][wid*8][0];   // wave-uniform LDS bases (HW adds lane*16B)
  short* bB = &Bs[0][wid*8][0];
  constexpr int nt = KK >> 6;

  const unsigned aLds = (unsigned)(uintptr_t)&As[0][0][0];
  const unsigned bLds = (unsigned)(uintptr_t)&Bs[0][0][0];
  const unsigned rowOffA = (unsigned)((wm*64 + fr)*128);
  const unsigned rowOffB = (unsigned)((wn*32 + fr)*128);
  const unsigned pc0 = (unsigned)(((fg  ) ^ (fr&7))*16);
  const unsigned pc1 = (unsigned)(((4+fg) ^ (fr&7))*16);

#define STAGE(tt, bb) do{                                             \
    const int k0_ = (tt) << 6;                                        \
    short* a_ = aB + (bb)*256*64;                                     \
    short* b_ = bB + (bb)*64*64;                                      \
    gload16(gA + k0_,          a_);                                   \
    gload16(gA + k0_ +   a64,  a_ +  64*64);                          \
    gload16(gA + k0_ + 2*a64,  a_ + 128*64);                          \
    gload16(gA + k0_ + 3*a64,  a_ + 192*64);                          \
    gload16(gB + k0_,          b_);                                   \
  }while(0)

  STAGE(0, 0);
  #pragma unroll
  for (int t = 0; t < nt; ++t){
    const int buf = t & 1;
    if (t + 1 < nt){
      STAGE(t+1, buf^1);
      asm volatile("s_waitcnt vmcnt(5)" ::: "memory");   // stage t landed; t+1 in flight
    } else {
      asm volatile("s_waitcnt vmcnt(0)" ::: "memory");
    }
    __builtin_amdgcn_s_barrier();      // all waves' stage-t writes visible
    const unsigned aoff = aLds + (unsigned)buf*32768u + rowOffA;
    const unsigned boff = bLds + (unsigned)buf*8192u  + rowOffB;
    #pragma unroll
    for (int kk=0; kk<2; ++kk){
      const unsigned pc = kk ? pc1 : pc0;
      short8 af[4], bq[2];
      #pragma unroll
      for (int m=0;m<4;m++) af[m] = ds_read_b128s(aoff + (unsigned)(m*2048) + pc);
      #pragma unroll
      for (int n=0;n<2;n++) bq[n] = ds_read_b128s(boff + (unsigned)(n*2048) + pc);
      asm volatile("s_waitcnt lgkmcnt(0)" ::: "memory");
      __builtin_amdgcn_sched_barrier(0);                 // rule #18: pin MFMA below the wait
      __builtin_amdgcn_s_setprio(1);
      #pragma unroll
      for (int m=0;m<4;m++)
        #pragma unroll
        for (int n=0;n<2;n++)
          acc[m][n] = __builtin_amdgcn_mfma_f32_16x16x32_bf16(af[m], bq[n], acc[m][n], 0,0,0);
      __builtin_amdgcn_s_setprio(0);
    }
    __builtin_amdgcn_s_barrier();      // reads of buf done before it is re-staged
  }
#undef STAGE

  #pragma unroll
  for (int n=0;n<2;n++){
    int gc = n0 + wn*32 + n*16 + fr;
    float bv = bias[gc];
    #pragma unroll
    for (int m=0;m<4;m++){
      int gr0 = m0 + wm*64 + m*16 + fg*4;
      #pragma unroll
      for (int i=0;i<4;i++){
        int R = gr0 + i;
        float v = acc[m][n][i] + bv;
        if (EPI==0){
          ((short*)outp)[(size_t)R*N + gc] = f2bf(v);
        } else if (EPI==1){
          int p = tok2pix(R); size_t idx=(size_t)p*CCH+gc;
          ((float*)outp)[idx] = res[idx] + v;
        } else if (EPI==2){
          // tanh-approx GELU (max dev ~3e-4 vs erf form; threshold 0.11)
          float u  = v + 0.044715f*v*v*v;
          float e  = __expf(1.5957691216057308f*u);   // e^(2*0.79788456*u)
          float th = 1.f - 2.f/(e+1.f);
          float gg = 0.5f*v*(1.f+th);
          ((short*)outp)[(size_t)R*N+gc] = f2bf(gg);
        } else {
          size_t idx=(size_t)R*CCH+gc;
          ((float*)outp)[idx] = res[idx] + v;
        }
      }
    }
  }
}

// ---- MFMA windowed attention: block = window, wave w -> heads w, w+4, w+8 ----
__global__ __launch_bounds__(256) void attn_mfma(const short* __restrict__ qkv,
    const float* __restrict__ rel_bias, short* __restrict__ attnout)
{
  __shared__ short Pl[4][64][68];
  __shared__ short Vt[4][32][68];
  __shared__ float lb[4][169];
  __shared__ int grp[64];
  const int wi = blockIdx.x;
  const int wid = threadIdx.x>>6, lane = threadIdx.x&63;
  const int fr = lane&15, fg = lane>>4;
  const int w = wi & 63, wh = w>>3, ww = w&7;
  if (threadIdx.x < 64){
    int t = threadIdx.x;
    int gv = 0;
    if (t < 49){
      int ai = t/7, aj = t%7;
      int hs = wh*7+ai, ws = ww*7+aj;
      int gh = hs<49?0:(hs<53?1:2);
      int gw = ws<49?0:(ws<53?1:2);
      gv = gh*3+gw;
    } else gv = -1;
    grp[t] = gv;
  }
  for (int t = lane; t < 32*15; t += 64){
    int d = t/15, j = 49 + t - d*15;
    Vt[wid][d][j] = 0;
  }
  __syncthreads();
  const size_t tbase = (size_t)wi*49;
  const float SCALE = 0.17677669529663687f;

  for (int hi=0; hi<3; ++hi){
    const int h = hi*4 + wid;
    for (int t = lane; t < 169; t += 64) lb[wid][t] = rel_bias[t*12 + h];
    for (int t = lane; t < 196; t += 64){
      int j = t>>2, d0 = (t&3)*8;
      short8 vv = *(const short8*)&qkv[(tbase+j)*1152 + 768 + h*32 + d0];
      #pragma unroll
      for (int s=0;s<8;s++) Vt[wid][d0+s][j] = vv[s];
    }
    short8 zf = {};
    short8 aq[4], bk[4];
    #pragma unroll
    for (int m=0;m<4;m++){
      int r = m*16+fr;
      aq[m] = (r<49) ? *(const short8*)&qkv[(tbase+r)*1152       + h*32 + fg*8] : zf;
      bk[m] = (r<49) ? *(const short8*)&qkv[(tbase+r)*1152 + 384 + h*32 + fg*8] : zf;
    }
    __syncthreads();   // (1) Vt/lb visible

    floatx4 sc[4][4];
    #pragma unroll
    for (int m=0;m<4;m++)
      #pragma unroll
      for (int n=0;n<4;n++)
        sc[m][n] = __builtin_amdgcn_mfma_f32_16x16x32_bf16(aq[m], bk[n], (floatx4){0.f,0.f,0.f,0.f}, 0,0,0);

    int ciC[4], cjC[4], gC[4], cvC[4];
    #pragma unroll
    for (int n=0;n<4;n++){
      int c = n*16+fr;
      ciC[n] = c/7; cjC[n] = c - ciC[n]*7;
      gC[n] = grp[c]; cvC[n] = (c<49);
    }
    #pragma unroll
    for (int m=0;m<4;m++){
      #pragma unroll
      for (int i=0;i<4;i++){
        int r = m*16 + fg*4 + i;
        int rv = (r<49);
        int ri = r/7, rj = r - ri*7;
        int gr = grp[r];
        float mxv = -3e30f;
        #pragma unroll
        for (int n=0;n<4;n++){
          float s;
          if (rv && cvC[n]){
            int dr = ri - ciC[n] + 6, dc = rj - cjC[n] + 6;
            s = sc[m][n][i]*SCALE + lb[wid][dr*13+dc];
            if (gr != gC[n]) s -= 100.f;
          } else s = -3e30f;
          sc[m][n][i] = s;
          mxv = fmaxf(mxv, s);
        }
        #pragma unroll
        for (int off=1;off<16;off<<=1) mxv = fmaxf(mxv, __shfl_xor(mxv, off));
        float sum = 0.f;
        #pragma unroll
        for (int n=0;n<4;n++){
          float e = __expf(sc[m][n][i]-mxv);
          sc[m][n][i] = e; sum += e;
        }
        #pragma unroll
        for (int off=1;off<16;off<<=1) sum += __shfl_xor(sum, off);
        float inv = 1.f/sum;
        #pragma unroll
        for (int n=0;n<4;n++)
          Pl[wid][r][n*16+fr] = f2bf(sc[m][n][i]*inv);
      }
    }
    __syncthreads();   // (2) P visible

    short8 pa[4][2], vb[2][2];
    #pragma unroll
    for (int m=0;m<4;m++)
      #pragma unroll
      for (int ks=0;ks<2;ks++)
        pa[m][ks] = *(const short8*)&Pl[wid][m*16+fr][ks*32+fg*8];
    #pragma unroll
    for (int n2=0;n2<2;n2++)
      #pragma unroll
      for (int ks=0;ks<2;ks++)
        vb[n2][ks] = *(const short8*)&Vt[wid][n2*16+fr][ks*32+fg*8];
    floatx4 oc[4][2];
    #pragma unroll
    for (int m=0;m<4;m++)
      #pragma unroll
      for (int n2=0;n2<2;n2++){
        oc[m][n2] = (floatx4){0.f,0.f,0.f,0.f};
        #pragma unroll
        for (int ks=0;ks<2;ks++)
          oc[m][n2] = __builtin_amdgcn_mfma_f32_16x16x32_bf16(pa[m][ks], vb[n2][ks], oc[m][n2], 0,0,0);
      }
    #pragma unroll
    for (int m=0;m<4;m++){
      #pragma unroll
      for (int i=0;i<4;i++){
        int r = m*16 + fg*4 + i;
        if (r < 49){
          #pragma unroll
          for (int n2=0;n2<2;n2++)
            attnout[(tbase+r)*384 + h*32 + n2*16 + fr] = f2bf(oc[m][n2][i]);
        }
      }
    }
    __syncthreads();   // (3) Vt reads done before next head's staging
  }
}

extern "C" void kernel_launch(void* const* d_in, const int* in_sizes, int n_in,
                              void* d_out, int out_size, void* d_ws, size_t ws_size,
                              hipStream_t stream)
{
  const float* x      = (const float*)d_in[0];
  const float* n1g    = (const float*)d_in[1];
  const float* n1b    = (const float*)d_in[2];
  const float* qkv_w  = (const float*)d_in[3];
  const float* qkv_b  = (const float*)d_in[4];
  const float* relb   = (const float*)d_in[5];
  const float* proj_w = (const float*)d_in[6];
  const float* proj_b = (const float*)d_in[7];
  const float* n2g    = (const float*)d_in[8];
  const float* n2b    = (const float*)d_in[9];
  const float* fc1_w  = (const float*)d_in[10];
  const float* fc1_b  = (const float*)d_in[11];
  const float* fc2_w  = (const float*)d_in[12];
  const float* fc2_b  = (const float*)d_in[13];

  char* ws = (char*)d_ws;
  const size_t SZ_XW  = (size_t)NTOK*CCH*2;
  const size_t SZ_QKV = (size_t)NTOK*1152*2;
  const size_t SZ_ATT = SZ_XW;
  const size_t SZ_Y   = (size_t)NTOK*CCH*4;

  short* xw    = (short*)(ws);
  short* qkvb  = (short*)(ws + SZ_XW);
  short* att   = (short*)(ws + SZ_XW + SZ_QKV);
  float* y     = (float*)(ws + SZ_XW + SZ_QKV + SZ_ATT);
  short* wbuf  = (short*)(ws + SZ_XW + SZ_QKV + SZ_ATT + SZ_Y);
  short* qkvWt = wbuf;                           // [1152][384]
  short* projWt= qkvWt + (size_t)1152*384;       // [384][384]
  short* fc1Wt = projWt + (size_t)384*384;       // [1536][384]
  short* fc2Wt = fc1Wt + (size_t)1536*384;       // [384][1536]
  short* hbuf  = qkvb;                           // [NTOK][1536]
  short* hin   = xw;                             // [NTOK][384]

  wtconv<<<dim3((384*1152+255)/256), dim3(256), 0, stream>>>(qkv_w, qkvWt, 384, 1152);
  wtconv<<<dim3((384*384 +255)/256), dim3(256), 0, stream>>>(proj_w, projWt, 384, 384);
  wtconv<<<dim3((384*1536+255)/256), dim3(256), 0, stream>>>(fc1_w, fc1Wt, 384, 1536);
  wtconv<<<dim3((1536*384+255)/256), dim3(256), 0, stream>>>(fc2_w, fc2Wt, 1536, 384);

  ln_kernel<1><<<dim3(NTOK/4), dim3(256), 0, stream>>>(x, n1g, n1b, xw);
  gemm8<0,384><<<dim3(18*196), dim3(512), 0, stream>>>(xw,  qkvWt, qkv_b, nullptr, qkvb, 1152, 18);
  attn_mfma<<<dim3(NBATCH*NW), dim3(256), 0, stream>>>(qkvb, relb, att);
  gemm8<1,384><<<dim3(6*196),  dim3(512), 0, stream>>>(att, projWt, proj_b, x, y, 384, 6);
  ln_kernel<0><<<dim3(NTOK/4), dim3(256), 0, stream>>>(y, n2g, n2b, hin);
  gemm8<2,384><<<dim3(24*196), dim3(512), 0, stream>>>(hin, fc1Wt, fc1_b, nullptr, hbuf, 1536, 24);
  gemm8<3,1536><<<dim3(6*196), dim3(512), 0, stream>>>(hbuf, fc2Wt, fc2_b, y, d_out, 384, 6);
}